// Round 4
// baseline (251.492 us; speedup 1.0000x reference)
//
#include <hip/hip_runtime.h>
#include <hip/hip_bf16.h>
#include <cstdint>
#include <math.h>

// ---------------------------------------------------------------------------
// MyMultiHeadAttention: q/k/v proj (merged bf16 MFMA GEMM, XCD panel swizzle)
// -> fused flash attention (swapped QK^T, 32 q/wave, in-register softmax+P,
// causal truncation, exact -1e9 mask semantics) -> output proj (f32 out).
// B=8 S=1024 D=1024 H=16 Dh=64.
// ---------------------------------------------------------------------------

typedef __bf16 bf16_t;
typedef __bf16 bf16x8 __attribute__((ext_vector_type(8)));
typedef __bf16 bf16x4 __attribute__((ext_vector_type(4)));
typedef float  f32x4  __attribute__((ext_vector_type(4)));

#define MFMA16(a, b, c) __builtin_amdgcn_mfma_f32_16x16x32_bf16((a), (b), (c), 0, 0, 0)
#define NEGV (-1e9f)

__device__ __forceinline__ void gl_lds16(const void* gp, void* lp) {
  __builtin_amdgcn_global_load_lds(
      (__attribute__((address_space(1))) void*)(gp),
      (__attribute__((address_space(3))) void*)(lp), 16, 0, 0);
}

__device__ __forceinline__ unsigned int pk2(float lo, float hi) {
  unsigned short a = __builtin_bit_cast(unsigned short, (bf16_t)lo);
  unsigned short b = __builtin_bit_cast(unsigned short, (bf16_t)hi);
  return (unsigned int)a | ((unsigned int)b << 16);
}

// ---------------- f32 -> bf16 bulk converts (8 elems/thread) ----------------
__device__ __forceinline__ void cvt_body(const float* __restrict__ in,
                                         bf16_t* __restrict__ out, int i, int n8) {
  if (i < n8) {
    const float4* p = reinterpret_cast<const float4*>(in) + (size_t)i * 2;
    float4 a = p[0], b = p[1];
    bf16x8 r = {(bf16_t)a.x, (bf16_t)a.y, (bf16_t)a.z, (bf16_t)a.w,
                (bf16_t)b.x, (bf16_t)b.y, (bf16_t)b.z, (bf16_t)b.w};
    *reinterpret_cast<bf16x8*>(out + (size_t)i * 8) = r;
  }
}

__global__ __launch_bounds__(256) void cvt_qkv(const float* __restrict__ a, const float* __restrict__ b,
                                               const float* __restrict__ c,
                                               bf16_t* __restrict__ oa, bf16_t* __restrict__ ob,
                                               bf16_t* __restrict__ oc, int n8) {
  const float* in = blockIdx.y == 0 ? a : (blockIdx.y == 1 ? b : c);
  bf16_t* out     = blockIdx.y == 0 ? oa : (blockIdx.y == 1 ? ob : oc);
  cvt_body(in, out, blockIdx.x * 256 + threadIdx.x, n8);
}

__global__ __launch_bounds__(256) void cvt_w4(const float* __restrict__ a, const float* __restrict__ b,
                                              const float* __restrict__ c, const float* __restrict__ d,
                                              bf16_t* __restrict__ oa, bf16_t* __restrict__ ob,
                                              bf16_t* __restrict__ oc, bf16_t* __restrict__ od, int n8) {
  const float* in = blockIdx.y == 0 ? a : (blockIdx.y == 1 ? b : (blockIdx.y == 2 ? c : d));
  bf16_t* out     = blockIdx.y == 0 ? oa : (blockIdx.y == 1 ? ob : (blockIdx.y == 2 ? oc : od));
  cvt_body(in, out, blockIdx.x * 256 + threadIdx.x, n8);
}

// ---- XCD panel swizzle: 8 N-tiles of one M-panel land on one XCD ----------
// r in [0,512): hw XCD = r%8 (512-multiple grids keep this per z-slice).
// Decode so that all bx share (by): by%8 == r%8.
__device__ __forceinline__ void panel_decode(int r, int& bx, int& by) {
  const int t8 = r >> 3;
  bx = t8 & 7;
  by = ((t8 >> 3) << 3) | (r & 7);
}

// ---------------- merged q/k/v projection GEMM ----------------
// grid (512, 3): z=0 q-proj (bias, x0.125 scale), z=1 k-proj (no bias),
// z=2 v-proj (bias, vt[b,h,d,s] scatter).  C[m,n] = sum_k A[m,k]*W[n,k].
__global__ __launch_bounds__(256) void gemm_qkv(const bf16_t* __restrict__ qbf,
                                                const bf16_t* __restrict__ kbf,
                                                const bf16_t* __restrict__ vbf,
                                                const bf16_t* __restrict__ wqb,
                                                const bf16_t* __restrict__ wkb,
                                                const bf16_t* __restrict__ wvb,
                                                const float* __restrict__ bq,
                                                const float* __restrict__ bv,
                                                bf16_t* __restrict__ qp,
                                                bf16_t* __restrict__ kp,
                                                bf16_t* __restrict__ vtw) {
  __shared__ bf16_t As[128 * 32];
  __shared__ bf16_t Bs[128 * 32];
  const int z = blockIdx.y;
  const bf16_t* A = z == 0 ? qbf : (z == 1 ? kbf : vbf);
  const bf16_t* W = z == 0 ? wqb : (z == 1 ? wkb : wvb);
  const int t = threadIdx.x;
  const int w = t >> 6, l = t & 63, lr = l & 15, lg = l >> 4;
  int bx, by;
  panel_decode((int)blockIdx.x, bx, by);
  const int m0 = by * 128, n0 = bx * 128;
  const int wm = (w >> 1) * 64, wn = (w & 1) * 64;
  const int K = 1024, N = 1024;

  f32x4 acc[4][4] = {};
  const bf16_t* Ag = A + (size_t)(m0 + (t >> 2)) * K + (t & 3) * 8;
  const bf16_t* Wg = W + (size_t)(n0 + (t >> 2)) * K + (t & 3) * 8;
  char* AsB = (char*)As;
  char* BsB = (char*)Bs;

  for (int kt = 0; kt < K; kt += 32) {
    gl_lds16(Ag + kt,                    AsB + t * 16);
    gl_lds16(Ag + kt + (size_t)64 * K,   AsB + 4096 + t * 16);
    gl_lds16(Wg + kt,                    BsB + t * 16);
    gl_lds16(Wg + kt + (size_t)64 * K,   BsB + 4096 + t * 16);
    asm volatile("s_waitcnt vmcnt(0)");
    __syncthreads();

    bf16x8 af[4], bfr[4];
#pragma unroll
    for (int mt = 0; mt < 4; mt++)
      af[mt] = *reinterpret_cast<const bf16x8*>(AsB + ((wm + mt * 16 + lr) * 32 + lg * 8) * 2);
#pragma unroll
    for (int nt = 0; nt < 4; nt++)
      bfr[nt] = *reinterpret_cast<const bf16x8*>(BsB + ((wn + nt * 16 + lr) * 32 + lg * 8) * 2);
#pragma unroll
    for (int mt = 0; mt < 4; mt++)
#pragma unroll
      for (int nt = 0; nt < 4; nt++)
        acc[mt][nt] = MFMA16(af[mt], bfr[nt], acc[mt][nt]);
    __syncthreads();
  }

#pragma unroll
  for (int nt = 0; nt < 4; nt++) {
    const int col = n0 + wn + nt * 16 + lr;
    const float bb = (z == 0) ? bq[col] : (z == 2 ? bv[col] : 0.0f);
#pragma unroll
    for (int mt = 0; mt < 4; mt++) {
#pragma unroll
      for (int i = 0; i < 4; i++) {
        const int row = m0 + wm + mt * 16 + lg * 4 + i;
        const float v = acc[mt][nt][i] + bb;
        if (z == 0) {
          // fold attention's /8 here: exact (power-of-2 scale commutes with
          // bf16 rounding) -> attention scores bitwise-match reference's /8.
          qp[(size_t)row * N + col] = (bf16_t)(v * 0.125f);
        } else if (z == 1) {
          kp[(size_t)row * N + col] = (bf16_t)v;
        } else {
          const int b = row >> 10, s = row & 1023;
          const int h = col >> 6, d = col & 63;
          vtw[(size_t)((b * 16 + h) * 64 + d) * 1024 + s] = (bf16_t)v;
        }
      }
    }
  }
}

// ---------------- final GEMM: f32 out, bias, panel swizzle ----------------
__global__ __launch_bounds__(256) void gemm_out(const bf16_t* __restrict__ A,
                                                const bf16_t* __restrict__ W,
                                                const float* __restrict__ bias,
                                                float* __restrict__ outp) {
  __shared__ bf16_t As[128 * 32];
  __shared__ bf16_t Bs[128 * 32];
  const int t = threadIdx.x;
  const int w = t >> 6, l = t & 63, lr = l & 15, lg = l >> 4;
  int bx, by;
  panel_decode((int)blockIdx.x, bx, by);
  const int m0 = by * 128, n0 = bx * 128;
  const int wm = (w >> 1) * 64, wn = (w & 1) * 64;
  const int K = 1024, N = 1024;

  f32x4 acc[4][4] = {};
  const bf16_t* Ag = A + (size_t)(m0 + (t >> 2)) * K + (t & 3) * 8;
  const bf16_t* Wg = W + (size_t)(n0 + (t >> 2)) * K + (t & 3) * 8;
  char* AsB = (char*)As;
  char* BsB = (char*)Bs;

  for (int kt = 0; kt < K; kt += 32) {
    gl_lds16(Ag + kt,                    AsB + t * 16);
    gl_lds16(Ag + kt + (size_t)64 * K,   AsB + 4096 + t * 16);
    gl_lds16(Wg + kt,                    BsB + t * 16);
    gl_lds16(Wg + kt + (size_t)64 * K,   BsB + 4096 + t * 16);
    asm volatile("s_waitcnt vmcnt(0)");
    __syncthreads();

    bf16x8 af[4], bfr[4];
#pragma unroll
    for (int mt = 0; mt < 4; mt++)
      af[mt] = *reinterpret_cast<const bf16x8*>(AsB + ((wm + mt * 16 + lr) * 32 + lg * 8) * 2);
#pragma unroll
    for (int nt = 0; nt < 4; nt++)
      bfr[nt] = *reinterpret_cast<const bf16x8*>(BsB + ((wn + nt * 16 + lr) * 32 + lg * 8) * 2);
#pragma unroll
    for (int mt = 0; mt < 4; mt++)
#pragma unroll
      for (int nt = 0; nt < 4; nt++)
        acc[mt][nt] = MFMA16(af[mt], bfr[nt], acc[mt][nt]);
    __syncthreads();
  }

#pragma unroll
  for (int nt = 0; nt < 4; nt++) {
    const int col = n0 + wn + nt * 16 + lr;
    const float bb = bias[col];
#pragma unroll
    for (int mt = 0; mt < 4; mt++)
#pragma unroll
      for (int i = 0; i < 4; i++) {
        const int row = m0 + wm + mt * 16 + lg * 4 + i;
        outp[(size_t)row * N + col] = acc[mt][nt][i] + bb;
      }
  }
}

// ---------------- in-register P pack + butterfly (16-lane groups) ----------
// s[nt][i] = P^T[key=nt*16+lg*4+i][q=lr]; output: two bf16x8 B-fragments.
__device__ __forceinline__ void pack_bfly(const f32x4 (&s)[4], int lg,
                                          bf16x8& pbv0, bf16x8& pbv1) {
  unsigned int u[4][2], sh[4][2];
#pragma unroll
  for (int nt = 0; nt < 4; nt++) {
    u[nt][0] = pk2(s[nt][0], s[nt][1]);
    u[nt][1] = pk2(s[nt][2], s[nt][3]);
  }
#pragma unroll
  for (int nt = 0; nt < 4; nt++) {
    sh[nt][0] = (unsigned int)__shfl_xor((int)u[nt][0], 16, 64);
    sh[nt][1] = (unsigned int)__shfl_xor((int)u[nt][1], 16, 64);
  }
  const bool ev = (lg & 1) == 0;
  unsigned int Y[8];
  Y[0] = ev ? u[0][0] : sh[1][0];  Y[1] = ev ? u[0][1] : sh[1][1];
  Y[2] = ev ? u[2][0] : sh[3][0];  Y[3] = ev ? u[2][1] : sh[3][1];
  Y[4] = ev ? sh[0][0] : u[1][0];  Y[5] = ev ? sh[0][1] : u[1][1];
  Y[6] = ev ? sh[2][0] : u[3][0];  Y[7] = ev ? sh[2][1] : u[3][1];
  const bool mid = (lg == 1) || (lg == 2);
#pragma unroll
  for (int j = 0; j < 8; j++) {
    const unsigned int z = (unsigned int)__shfl_xor((int)Y[j], 48, 64);
    Y[j] = mid ? z : Y[j];
  }
  union U8 { unsigned int u[4]; bf16x8 v; };
  U8 p0, p1;
  p0.u[0] = Y[0]; p0.u[1] = Y[1]; p0.u[2] = Y[4]; p0.u[3] = Y[5];
  p1.u[0] = Y[2]; p1.u[1] = Y[3]; p1.u[2] = Y[6]; p1.u[3] = Y[7];
  pbv0 = p0.v;
  pbv1 = p1.v;
}

// ---------------- fused flash attention (2 q-sets per wave) ----------------
// Grid 1024: bh = (L&7) + 8*(L>>6)  (16 bh per XCD -> K/V L2-resident),
// j = (L>>3)&7, q0 = j*128.  4 waves x 32 q-rows (two 16-row sets/wave).
// qp comes pre-scaled by 0.125 (folded into q-projection, exact).
__global__ __launch_bounds__(256) void attn_fused(const bf16_t* __restrict__ qp,
                                                  const bf16_t* __restrict__ kp,
                                                  const bf16_t* __restrict__ vt,
                                                  const int* __restrict__ pad,
                                                  bf16_t* __restrict__ outp) {
  __shared__ bf16_t Ks[2][64 * 64];   // [key][dh], XOR-swizzled
  __shared__ bf16_t Vts[2][64 * 64];  // [dh][key], XOR-swizzled
  __shared__ int padI[1024];
  __shared__ int sf[4];
  const int t = threadIdx.x, w = t >> 6, l = t & 63, lr = l & 15, lg = l >> 4;
  const int L = (int)blockIdx.x;
  const int bh = (L & 7) + ((L >> 6) << 3);
  const int j = (L >> 3) & 7;
  const int b = bh >> 4, h = bh & 15;
  const int q0 = j * 128;

  const int srow = t >> 3, sc = t & 7;
  const int gc = sc ^ (srow & 7);  // pre-swizzled global chunk
  const bf16_t* kgb = kp + (size_t)(b * 1024 + srow) * 1024 + h * 64 + gc * 8;
  const bf16_t* vgb = vt + (size_t)(bh * 64 + srow) * 1024 + gc * 8;

  auto stage = [&](int bufi, int k0s) {
    char* Kd = (char*)(Ks[bufi]);
    char* Vd = (char*)(Vts[bufi]);
    gl_lds16(kgb + (size_t)k0s * 1024,        Kd + t * 16);
    gl_lds16(kgb + (size_t)(k0s + 32) * 1024, Kd + 4096 + t * 16);
    gl_lds16(vgb + k0s,                       Vd + t * 16);
    gl_lds16(vgb + k0s + (size_t)32 * 1024,   Vd + 4096 + t * 16);
  };

  // degenerate-row check: any unpadded key in [0, q0]?
  bool un = false;
  for (int jj = t; jj <= q0; jj += 256) un |= (pad[b * 1024 + jj] == 0);
  const bool anyun = __any(un);
  if (l == 0) sf[w] = anyun ? 1 : 0;

  stage(0, 0);
  gl_lds16(pad + b * 1024 + t * 4, (char*)padI + t * 16);

  // Q B-fragments for both 16-row sets (col = q-row = lr, k = dh)
  const int qr0 = q0 + w * 32 + lr;        // set-0 lane q row
  const int qr1 = qr0 + 16;                // set-1 lane q row
  const bf16_t* qg0 = qp + (size_t)(b * 1024 + qr0) * 1024 + h * 64 + lg * 8;
  const bf16_t* qg1 = qp + (size_t)(b * 1024 + qr1) * 1024 + h * 64 + lg * 8;
  const bf16x8 qa00 = *reinterpret_cast<const bf16x8*>(qg0);
  const bf16x8 qa01 = *reinterpret_cast<const bf16x8*>(qg0 + 32);
  const bf16x8 qa10 = *reinterpret_cast<const bf16x8*>(qg1);
  const bf16x8 qa11 = *reinterpret_cast<const bf16x8*>(qg1 + 32);

  __syncthreads();  // sf ready; drains tile-0 staging + padI + qa
  const int ktEnd = (sf[0] | sf[1] | sf[2] | sf[3]) ? (2 * j + 2) : 16;

  f32x4 o0[4] = {}, o1[4] = {};
  float m0_ = -INFINITY, ld0 = 0.0f;
  float m1_ = -INFINITY, ld1 = 0.0f;

  for (int kt = 0; kt < ktEnd; ++kt) {
    const int cur = kt & 1;
    if (kt + 1 < ktEnd) {
      stage(cur ^ 1, (kt + 1) * 64);
      asm volatile("s_waitcnt vmcnt(4)" ::: "memory");
    } else {
      asm volatile("s_waitcnt vmcnt(0)" ::: "memory");
    }
    __builtin_amdgcn_s_barrier();

    const char* Kb = (const char*)(Ks[cur]);
    const char* Vb = (const char*)(Vts[cur]);
    const int k0 = kt * 64;

    // S^T = K * Q^T for both sets; K-fragments shared
    f32x4 s0[4] = {}, s1[4] = {};
#pragma unroll
    for (int nt = 0; nt < 4; nt++) {
      const int row = nt * 16 + lr;
      const int sw = (row & 7) << 4;
      bf16x8 kb0 = *reinterpret_cast<const bf16x8*>(Kb + row * 128 + ((lg * 16) ^ sw));
      bf16x8 kb1 = *reinterpret_cast<const bf16x8*>(Kb + row * 128 + ((lg * 16 + 64) ^ sw));
      s0[nt] = MFMA16(kb0, qa00, s0[nt]);
      s0[nt] = MFMA16(kb1, qa01, s0[nt]);
      s1[nt] = MFMA16(kb0, qa10, s1[nt]);
      s1[nt] = MFMA16(kb1, qa11, s1[nt]);
    }

    // masking — reference f32 arithmetic exactly (qp pre-scaled by 1/8)
    const bool nc0 = (k0 + 63 > q0 + w * 32);
    const bool nc1 = (k0 + 63 > q0 + w * 32 + 16);
#pragma unroll
    for (int nt = 0; nt < 4; nt++) {
      const int kc4 = k0 + nt * 16 + lg * 4;
      const int4 pd = *reinterpret_cast<const int4*>(&padI[kc4]);
      const int pdv[4] = {pd.x, pd.y, pd.z, pd.w};
#pragma unroll
      for (int i = 0; i < 4; i++) {
        float v0 = s0[nt][i];
        float v1 = s1[nt][i];
        if (pdv[i]) { v0 = NEGV; v1 = NEGV; }
        if (nc0 && (kc4 + i > qr0)) v0 += NEGV;
        if (nc1 && (kc4 + i > qr1)) v1 += NEGV;
        s0[nt][i] = v0;
        s1[nt][i] = v1;
      }
    }

    // row max per set (independent chains -> ILP)
    float mx0 = s0[0][0], mx1 = s1[0][0];
#pragma unroll
    for (int nt = 0; nt < 4; nt++)
#pragma unroll
      for (int i = 0; i < 4; i++) {
        mx0 = fmaxf(mx0, s0[nt][i]);
        mx1 = fmaxf(mx1, s1[nt][i]);
      }
    mx0 = fmaxf(mx0, __shfl_xor(mx0, 16, 64));
    mx1 = fmaxf(mx1, __shfl_xor(mx1, 16, 64));
    mx0 = fmaxf(mx0, __shfl_xor(mx0, 32, 64));
    mx1 = fmaxf(mx1, __shfl_xor(mx1, 32, 64));

    const bool act0 = !__all(mx0 <= m0_ - 88.0f);
    const bool act1 = !__all(mx1 <= m1_ - 88.0f);

    if (act0 || act1) {
      bf16x8 pb00, pb01, pb10, pb11;
      if (act0) {
        if (!__all(mx0 <= m0_ + 8.0f)) {  // defer-max
          const float mn = fmaxf(m0_, mx0);
          const float scl = __expf(m0_ - mn);
          m0_ = mn;
          ld0 *= scl;
#pragma unroll
          for (int nt = 0; nt < 4; nt++) o0[nt] *= scl;
        }
        float a = 0.0f;
#pragma unroll
        for (int nt = 0; nt < 4; nt++)
#pragma unroll
          for (int i = 0; i < 4; i++) {
            const float p = __expf(s0[nt][i] - m0_);
            s0[nt][i] = p;
            a += p;
          }
        a += __shfl_xor(a, 16, 64);
        a += __shfl_xor(a, 32, 64);
        ld0 += a;
        pack_bfly(s0, lg, pb00, pb01);
      }
      if (act1) {
        if (!__all(mx1 <= m1_ + 8.0f)) {
          const float mn = fmaxf(m1_, mx1);
          const float scl = __expf(m1_ - mn);
          m1_ = mn;
          ld1 *= scl;
#pragma unroll
          for (int nt = 0; nt < 4; nt++) o1[nt] *= scl;
        }
        float a = 0.0f;
#pragma unroll
        for (int nt = 0; nt < 4; nt++)
#pragma unroll
          for (int i = 0; i < 4; i++) {
            const float p = __expf(s1[nt][i] - m1_);
            s1[nt][i] = p;
            a += p;
          }
        a += __shfl_xor(a, 16, 64);
        a += __shfl_xor(a, 32, 64);
        ld1 += a;
        pack_bfly(s1, lg, pb10, pb11);
      }

      // PV: O^T[d][q] += V^T[d][k] * P^T[k][q]; V-fragments shared
#pragma unroll
      for (int nt = 0; nt < 4; nt++) {
        const int vrow = nt * 16 + lr;
        const int vsw = (vrow & 7) << 4;
        bf16x8 vf0 = *reinterpret_cast<const bf16x8*>(Vb + vrow * 128 + ((lg * 16) ^ vsw));
        bf16x8 vf1 = *reinterpret_cast<const bf16x8*>(Vb + vrow * 128 + ((64 + lg * 16) ^ vsw));
        if (act0) {
          o0[nt] = MFMA16(vf0, pb00, o0[nt]);
          o0[nt] = MFMA16(vf1, pb01, o0[nt]);
        }
        if (act1) {
          o1[nt] = MFMA16(vf0, pb10, o1[nt]);
          o1[nt] = MFMA16(vf1, pb11, o1[nt]);
        }
      }
    }
    __builtin_amdgcn_s_barrier();  // protect buf[cur] before next prefetch
  }

  // epilogue: o^T[d = nt*16+lg*4+i][q], normalize, 8B vector stores
  const float r0 = 1.0f / ld0, r1 = 1.0f / ld1;
#pragma unroll
  for (int nt = 0; nt < 4; nt++) {
    bf16x4 v0 = {(bf16_t)(o0[nt][0] * r0), (bf16_t)(o0[nt][1] * r0),
                 (bf16_t)(o0[nt][2] * r0), (bf16_t)(o0[nt][3] * r0)};
    bf16x4 v1 = {(bf16_t)(o1[nt][0] * r1), (bf16_t)(o1[nt][1] * r1),
                 (bf16_t)(o1[nt][2] * r1), (bf16_t)(o1[nt][3] * r1)};
    *reinterpret_cast<bf16x4*>(outp + (size_t)(b * 1024 + qr0) * 1024 + h * 64 + nt * 16 + lg * 4) = v0;
    *reinterpret_cast<bf16x4*>(outp + (size_t)(b * 1024 + qr1) * 1024 + h * 64 + nt * 16 + lg * 4) = v1;
  }
}

// ---------------------------------------------------------------------------
extern "C" void kernel_launch(void* const* d_in, const int* in_sizes, int n_in,
                              void* d_out, int out_size, void* d_ws, size_t ws_size,
                              hipStream_t stream) {
  const float* q   = (const float*)d_in[0];
  const float* k   = (const float*)d_in[1];
  const float* v   = (const float*)d_in[2];
  const int*   pad = (const int*)d_in[3];
  const float* wq  = (const float*)d_in[5];
  const float* bq  = (const float*)d_in[6];
  const float* wk  = (const float*)d_in[7];
  const float* wv  = (const float*)d_in[8];
  const float* bv  = (const float*)d_in[9];
  const float* wo  = (const float*)d_in[10];
  const float* bo  = (const float*)d_in[11];

  const int M = 8192, N = 1024;
  const int nBig = M * N;
  const int nW   = N * 1024;

  char* ws = (char*)d_ws;
  const size_t MiB = 1024 * 1024;
  bf16_t* qbf = (bf16_t*)(ws + 0 * MiB);
  bf16_t* kbf = (bf16_t*)(ws + 16 * MiB);
  bf16_t* vbf = (bf16_t*)(ws + 32 * MiB);
  bf16_t* qp  = (bf16_t*)(ws + 48 * MiB);
  bf16_t* kp  = (bf16_t*)(ws + 64 * MiB);
  bf16_t* vtw = (bf16_t*)(ws + 80 * MiB);
  bf16_t* wqb = (bf16_t*)(ws + 96 * MiB);
  bf16_t* wkb = (bf16_t*)(ws + 98 * MiB);
  bf16_t* wvb = (bf16_t*)(ws + 100 * MiB);
  bf16_t* wob = (bf16_t*)(ws + 102 * MiB);
  bf16_t* attnO = qbf;  // qbf dead after q-projection

  cvt_qkv<<<dim3(nBig / 2048, 3), 256, 0, stream>>>(q, k, v, qbf, kbf, vbf, nBig / 8);
  cvt_w4 <<<dim3(nW / 2048, 4), 256, 0, stream>>>(wq, wk, wv, wo, wqb, wkb, wvb, wob, nW / 8);

  gemm_qkv<<<dim3(512, 3), 256, 0, stream>>>(qbf, kbf, vbf, wqb, wkb, wvb, bq, bv, qp, kp, vtw);

  attn_fused<<<1024, 256, 0, stream>>>(qp, kp, vtw, pad, attnO);

  gemm_out<<<512, 256, 0, stream>>>(attnO, wob, bo, (float*)d_out);
}

// Round 5
// 201.488 us; speedup vs baseline: 1.2482x; 1.2482x over previous
//
#include <hip/hip_runtime.h>
#include <hip/hip_bf16.h>
#include <cstdint>
#include <math.h>

// ---------------------------------------------------------------------------
// MyMultiHeadAttention: q/k/v proj (merged bf16 MFMA GEMM, XCD panel swizzle,
// q pre-scaled by 1/8) -> fused flash attention (paired causal q-tiles,
// 8 waves/block, swapped QK^T, in-register softmax+P, exact -1e9 semantics)
// -> output proj (f32 out).  B=8 S=1024 D=1024 H=16 Dh=64.
// ---------------------------------------------------------------------------

typedef __bf16 bf16_t;
typedef __bf16 bf16x8 __attribute__((ext_vector_type(8)));
typedef __bf16 bf16x4 __attribute__((ext_vector_type(4)));
typedef float  f32x4  __attribute__((ext_vector_type(4)));

#define MFMA16(a, b, c) __builtin_amdgcn_mfma_f32_16x16x32_bf16((a), (b), (c), 0, 0, 0)
#define NEGV (-1e9f)

__device__ __forceinline__ void gl_lds16(const void* gp, void* lp) {
  __builtin_amdgcn_global_load_lds(
      (__attribute__((address_space(1))) void*)(gp),
      (__attribute__((address_space(3))) void*)(lp), 16, 0, 0);
}

__device__ __forceinline__ unsigned int pk2(float lo, float hi) {
  unsigned short a = __builtin_bit_cast(unsigned short, (bf16_t)lo);
  unsigned short b = __builtin_bit_cast(unsigned short, (bf16_t)hi);
  return (unsigned int)a | ((unsigned int)b << 16);
}

// ---------------- f32 -> bf16 bulk converts (8 elems/thread) ----------------
__device__ __forceinline__ void cvt_body(const float* __restrict__ in,
                                         bf16_t* __restrict__ out, int i, int n8) {
  if (i < n8) {
    const float4* p = reinterpret_cast<const float4*>(in) + (size_t)i * 2;
    float4 a = p[0], b = p[1];
    bf16x8 r = {(bf16_t)a.x, (bf16_t)a.y, (bf16_t)a.z, (bf16_t)a.w,
                (bf16_t)b.x, (bf16_t)b.y, (bf16_t)b.z, (bf16_t)b.w};
    *reinterpret_cast<bf16x8*>(out + (size_t)i * 8) = r;
  }
}

__global__ __launch_bounds__(256) void cvt_qkv(const float* __restrict__ a, const float* __restrict__ b,
                                               const float* __restrict__ c,
                                               bf16_t* __restrict__ oa, bf16_t* __restrict__ ob,
                                               bf16_t* __restrict__ oc, int n8) {
  const float* in = blockIdx.y == 0 ? a : (blockIdx.y == 1 ? b : c);
  bf16_t* out     = blockIdx.y == 0 ? oa : (blockIdx.y == 1 ? ob : oc);
  cvt_body(in, out, blockIdx.x * 256 + threadIdx.x, n8);
}

__global__ __launch_bounds__(256) void cvt_w4(const float* __restrict__ a, const float* __restrict__ b,
                                              const float* __restrict__ c, const float* __restrict__ d,
                                              bf16_t* __restrict__ oa, bf16_t* __restrict__ ob,
                                              bf16_t* __restrict__ oc, bf16_t* __restrict__ od, int n8) {
  const float* in = blockIdx.y == 0 ? a : (blockIdx.y == 1 ? b : (blockIdx.y == 2 ? c : d));
  bf16_t* out     = blockIdx.y == 0 ? oa : (blockIdx.y == 1 ? ob : (blockIdx.y == 2 ? oc : od));
  cvt_body(in, out, blockIdx.x * 256 + threadIdx.x, n8);
}

// ---- XCD panel swizzle: 8 N-tiles of one M-panel land on one XCD ----------
__device__ __forceinline__ void panel_decode(int r, int& bx, int& by) {
  const int t8 = r >> 3;
  bx = t8 & 7;
  by = ((t8 >> 3) << 3) | (r & 7);
}

// ---------------- merged q/k/v projection GEMM ----------------
// grid (512, 3): z=0 q-proj (bias, x0.125), z=1 k-proj, z=2 v-proj (vt scatter)
__global__ __launch_bounds__(256) void gemm_qkv(const bf16_t* __restrict__ qbf,
                                                const bf16_t* __restrict__ kbf,
                                                const bf16_t* __restrict__ vbf,
                                                const bf16_t* __restrict__ wqb,
                                                const bf16_t* __restrict__ wkb,
                                                const bf16_t* __restrict__ wvb,
                                                const float* __restrict__ bq,
                                                const float* __restrict__ bv,
                                                bf16_t* __restrict__ qp,
                                                bf16_t* __restrict__ kp,
                                                bf16_t* __restrict__ vtw) {
  __shared__ bf16_t As[128 * 32];
  __shared__ bf16_t Bs[128 * 32];
  const int z = blockIdx.y;
  const bf16_t* A = z == 0 ? qbf : (z == 1 ? kbf : vbf);
  const bf16_t* W = z == 0 ? wqb : (z == 1 ? wkb : wvb);
  const int t = threadIdx.x;
  const int w = t >> 6, l = t & 63, lr = l & 15, lg = l >> 4;
  int bx, by;
  panel_decode((int)blockIdx.x, bx, by);
  const int m0 = by * 128, n0 = bx * 128;
  const int wm = (w >> 1) * 64, wn = (w & 1) * 64;
  const int K = 1024, N = 1024;

  f32x4 acc[4][4] = {};
  const bf16_t* Ag = A + (size_t)(m0 + (t >> 2)) * K + (t & 3) * 8;
  const bf16_t* Wg = W + (size_t)(n0 + (t >> 2)) * K + (t & 3) * 8;
  char* AsB = (char*)As;
  char* BsB = (char*)Bs;

  for (int kt = 0; kt < K; kt += 32) {
    gl_lds16(Ag + kt,                    AsB + t * 16);
    gl_lds16(Ag + kt + (size_t)64 * K,   AsB + 4096 + t * 16);
    gl_lds16(Wg + kt,                    BsB + t * 16);
    gl_lds16(Wg + kt + (size_t)64 * K,   BsB + 4096 + t * 16);
    asm volatile("s_waitcnt vmcnt(0)");
    __syncthreads();

    bf16x8 af[4], bfr[4];
#pragma unroll
    for (int mt = 0; mt < 4; mt++)
      af[mt] = *reinterpret_cast<const bf16x8*>(AsB + ((wm + mt * 16 + lr) * 32 + lg * 8) * 2);
#pragma unroll
    for (int nt = 0; nt < 4; nt++)
      bfr[nt] = *reinterpret_cast<const bf16x8*>(BsB + ((wn + nt * 16 + lr) * 32 + lg * 8) * 2);
#pragma unroll
    for (int mt = 0; mt < 4; mt++)
#pragma unroll
      for (int nt = 0; nt < 4; nt++)
        acc[mt][nt] = MFMA16(af[mt], bfr[nt], acc[mt][nt]);
    __syncthreads();
  }

#pragma unroll
  for (int nt = 0; nt < 4; nt++) {
    const int col = n0 + wn + nt * 16 + lr;
    const float bb = (z == 0) ? bq[col] : (z == 2 ? bv[col] : 0.0f);
#pragma unroll
    for (int mt = 0; mt < 4; mt++) {
#pragma unroll
      for (int i = 0; i < 4; i++) {
        const int row = m0 + wm + mt * 16 + lg * 4 + i;
        const float v = acc[mt][nt][i] + bb;
        if (z == 0) {
          // fold attention's /8 here: exact (pow-2 scale commutes w/ bf16 rnd)
          qp[(size_t)row * N + col] = (bf16_t)(v * 0.125f);
        } else if (z == 1) {
          kp[(size_t)row * N + col] = (bf16_t)v;
        } else {
          const int b = row >> 10, s = row & 1023;
          const int h = col >> 6, d = col & 63;
          vtw[(size_t)((b * 16 + h) * 64 + d) * 1024 + s] = (bf16_t)v;
        }
      }
    }
  }
}

// ---------------- final GEMM: f32 out, bias, panel swizzle ----------------
__global__ __launch_bounds__(256) void gemm_out(const bf16_t* __restrict__ A,
                                                const bf16_t* __restrict__ W,
                                                const float* __restrict__ bias,
                                                float* __restrict__ outp) {
  __shared__ bf16_t As[128 * 32];
  __shared__ bf16_t Bs[128 * 32];
  const int t = threadIdx.x;
  const int w = t >> 6, l = t & 63, lr = l & 15, lg = l >> 4;
  int bx, by;
  panel_decode((int)blockIdx.x, bx, by);
  const int m0 = by * 128, n0 = bx * 128;
  const int wm = (w >> 1) * 64, wn = (w & 1) * 64;
  const int K = 1024, N = 1024;

  f32x4 acc[4][4] = {};
  const bf16_t* Ag = A + (size_t)(m0 + (t >> 2)) * K + (t & 3) * 8;
  const bf16_t* Wg = W + (size_t)(n0 + (t >> 2)) * K + (t & 3) * 8;
  char* AsB = (char*)As;
  char* BsB = (char*)Bs;

  for (int kt = 0; kt < K; kt += 32) {
    gl_lds16(Ag + kt,                    AsB + t * 16);
    gl_lds16(Ag + kt + (size_t)64 * K,   AsB + 4096 + t * 16);
    gl_lds16(Wg + kt,                    BsB + t * 16);
    gl_lds16(Wg + kt + (size_t)64 * K,   BsB + 4096 + t * 16);
    asm volatile("s_waitcnt vmcnt(0)");
    __syncthreads();

    bf16x8 af[4], bfr[4];
#pragma unroll
    for (int mt = 0; mt < 4; mt++)
      af[mt] = *reinterpret_cast<const bf16x8*>(AsB + ((wm + mt * 16 + lr) * 32 + lg * 8) * 2);
#pragma unroll
    for (int nt = 0; nt < 4; nt++)
      bfr[nt] = *reinterpret_cast<const bf16x8*>(BsB + ((wn + nt * 16 + lr) * 32 + lg * 8) * 2);
#pragma unroll
    for (int mt = 0; mt < 4; mt++)
#pragma unroll
      for (int nt = 0; nt < 4; nt++)
        acc[mt][nt] = MFMA16(af[mt], bfr[nt], acc[mt][nt]);
    __syncthreads();
  }

#pragma unroll
  for (int nt = 0; nt < 4; nt++) {
    const int col = n0 + wn + nt * 16 + lr;
    const float bb = bias[col];
#pragma unroll
    for (int mt = 0; mt < 4; mt++)
#pragma unroll
      for (int i = 0; i < 4; i++) {
        const int row = m0 + wm + mt * 16 + lg * 4 + i;
        outp[(size_t)row * N + col] = acc[mt][nt][i] + bb;
      }
  }
}

// ---------------- in-register P pack + butterfly (16-lane groups) ----------
__device__ __forceinline__ void pack_bfly(const f32x4 (&s)[4], int lg,
                                          bf16x8& pbv0, bf16x8& pbv1) {
  unsigned int u[4][2], sh[4][2];
#pragma unroll
  for (int nt = 0; nt < 4; nt++) {
    u[nt][0] = pk2(s[nt][0], s[nt][1]);
    u[nt][1] = pk2(s[nt][2], s[nt][3]);
  }
#pragma unroll
  for (int nt = 0; nt < 4; nt++) {
    sh[nt][0] = (unsigned int)__shfl_xor((int)u[nt][0], 16, 64);
    sh[nt][1] = (unsigned int)__shfl_xor((int)u[nt][1], 16, 64);
  }
  const bool ev = (lg & 1) == 0;
  unsigned int Y[8];
  Y[0] = ev ? u[0][0] : sh[1][0];  Y[1] = ev ? u[0][1] : sh[1][1];
  Y[2] = ev ? u[2][0] : sh[3][0];  Y[3] = ev ? u[2][1] : sh[3][1];
  Y[4] = ev ? sh[0][0] : u[1][0];  Y[5] = ev ? sh[0][1] : u[1][1];
  Y[6] = ev ? sh[2][0] : u[3][0];  Y[7] = ev ? sh[2][1] : u[3][1];
  const bool mid = (lg == 1) || (lg == 2);
#pragma unroll
  for (int j = 0; j < 8; j++) {
    const unsigned int z = (unsigned int)__shfl_xor((int)Y[j], 48, 64);
    Y[j] = mid ? z : Y[j];
  }
  union U8 { unsigned int u[4]; bf16x8 v; };
  U8 p0, p1;
  p0.u[0] = Y[0]; p0.u[1] = Y[1]; p0.u[2] = Y[4]; p0.u[3] = Y[5];
  p1.u[0] = Y[2]; p1.u[1] = Y[3]; p1.u[2] = Y[6]; p1.u[3] = Y[7];
  pbv0 = p0.v;
  pbv1 = p1.v;
}

// ---------------- fused flash attention (paired q-tiles, 8 waves) ----------
// Grid 1024: bh = (L&7)+8*(L>>6) (16 bh/XCD), j = (L>>3)&7.
// Block handles q-tiles lo=j (waves 4-7) and hi=15-j (waves 0-3), 64 rows each,
// sharing one K/V staging stream over k-tiles 0..hi.  Work/block ~uniform (17
// tile-computations), 4 blocks/CU x 8 waves = full occupancy.
// qp comes pre-scaled by 0.125 (folded into q-projection, exact).
__global__ __launch_bounds__(512, 8) void attn_fused(const bf16_t* __restrict__ qp,
                                                     const bf16_t* __restrict__ kp,
                                                     const bf16_t* __restrict__ vt,
                                                     const int* __restrict__ pad,
                                                     bf16_t* __restrict__ outp) {
  __shared__ bf16_t Ks[2][64 * 64];   // [key][dh], XOR-swizzled
  __shared__ bf16_t Vts[2][64 * 64];  // [dh][key], XOR-swizzled
  __shared__ int padI[1024];
  __shared__ int sfl[8], sfh[8];
  const int t = threadIdx.x, w = t >> 6, l = t & 63, lr = l & 15, lg = l >> 4;
  const int L = (int)blockIdx.x;
  const int bh = (L & 7) + ((L >> 6) << 3);
  const int j = (L >> 3) & 7;
  const int b = bh >> 4, h = bh & 15;
  const int lo = j, hi = 15 - j;

  // staging: 512 thr x 16B covers one 64x64 bf16 tile per gl_lds16 call.
  const int srow = t >> 3, sc = t & 7;
  const int gc = sc ^ (srow & 7);  // pre-swizzled global chunk
  const bf16_t* kgb = kp + (size_t)(b * 1024 + srow) * 1024 + h * 64 + gc * 8;
  const bf16_t* vgb = vt + (size_t)(bh * 64 + srow) * 1024 + gc * 8;

  auto stage = [&](int bufi, int k0s) {
    gl_lds16(kgb + (size_t)k0s * 1024, (char*)(Ks[bufi]) + t * 16);
    gl_lds16(vgb + k0s,                (char*)(Vts[bufi]) + t * 16);
  };

  // degenerate-row checks: any unpadded key in [0, lo*64] / [0, hi*64]?
  bool unl = false, unh = false;
  for (int jj = t; jj <= hi * 64; jj += 512) {
    const bool u = (pad[b * 1024 + jj] == 0);
    unh |= u;
    unl |= (u && (jj <= lo * 64));
  }
  const bool al = __any(unl), ah = __any(unh);
  if (l == 0) { sfl[w] = al ? 1 : 0; sfh[w] = ah ? 1 : 0; }

  stage(0, 0);
  if (t < 256) gl_lds16(pad + b * 1024 + t * 4, (char*)padI + t * 16);

  // this wave's q-tile: waves 0-3 -> hi, waves 4-7 -> lo
  const int mytile = (w < 4) ? hi : lo;
  const int qrow_l = mytile * 64 + (w & 3) * 16 + lr;  // lane's q row
  const int base16 = mytile * 64 + (w & 3) * 16;
  const bf16_t* qg = qp + (size_t)(b * 1024 + qrow_l) * 1024 + h * 64 + lg * 8;
  const bf16x8 qa0 = *reinterpret_cast<const bf16x8*>(qg);
  const bf16x8 qa1 = *reinterpret_cast<const bf16x8*>(qg + 32);

  __syncthreads();  // sf ready; drains tile-0 staging + padI
  int ul = 0, uh = 0;
#pragma unroll
  for (int i = 0; i < 8; i++) { ul |= sfl[i]; uh |= sfh[i]; }
  const bool mydeg = (w < 4) ? (uh == 0) : (ul == 0);
  const int ktEnd = (ul == 0) ? 16 : (hi + 1);

  f32x4 o[4] = {};
  float m_ = -INFINITY, ld_ = 0.0f;

  for (int kt = 0; kt < ktEnd; ++kt) {
    const int cur = kt & 1;
    if (kt + 1 < ktEnd) {
      stage(cur ^ 1, (kt + 1) * 64);
      asm volatile("s_waitcnt vmcnt(2)" ::: "memory");
    } else {
      asm volatile("s_waitcnt vmcnt(0)" ::: "memory");
    }
    __builtin_amdgcn_s_barrier();

    if (kt <= mytile || mydeg) {
      const char* Kb = (const char*)(Ks[cur]);
      const char* Vb = (const char*)(Vts[cur]);
      const int k0 = kt * 64;

      // S^T = K * Q^T : s[nt][i] = score[key=k0+nt*16+lg*4+i][q=qrow_l]
      f32x4 s[4] = {};
#pragma unroll
      for (int nt = 0; nt < 4; nt++) {
        const int row = nt * 16 + lr;
        const int sw = (row & 7) << 4;
        bf16x8 kb0 = *reinterpret_cast<const bf16x8*>(Kb + row * 128 + ((lg * 16) ^ sw));
        bf16x8 kb1 = *reinterpret_cast<const bf16x8*>(Kb + row * 128 + ((lg * 16 + 64) ^ sw));
        s[nt] = MFMA16(kb0, qa0, s[nt]);
        s[nt] = MFMA16(kb1, qa1, s[nt]);
      }

      // masking — reference f32 arithmetic exactly (qp pre-scaled by 1/8)
      const bool nc = (k0 + 63 > base16);
#pragma unroll
      for (int nt = 0; nt < 4; nt++) {
        const int kc4 = k0 + nt * 16 + lg * 4;
        const int4 pd = *reinterpret_cast<const int4*>(&padI[kc4]);
        const int pdv[4] = {pd.x, pd.y, pd.z, pd.w};
#pragma unroll
        for (int i = 0; i < 4; i++) {
          float v = s[nt][i];
          if (pdv[i]) v = NEGV;
          if (nc && (kc4 + i > qrow_l)) v += NEGV;
          s[nt][i] = v;
        }
      }

      // row max: 15 reg-local fmax + 2 shfl
      float mx = s[0][0];
#pragma unroll
      for (int nt = 0; nt < 4; nt++)
#pragma unroll
        for (int i = 0; i < 4; i++) mx = fmaxf(mx, s[nt][i]);
      mx = fmaxf(mx, __shfl_xor(mx, 16, 64));
      mx = fmaxf(mx, __shfl_xor(mx, 32, 64));

      if (!__all(mx <= m_ - 88.0f)) {          // dynamic underflow skip
        if (!__all(mx <= m_ + 8.0f)) {         // defer-max rescale
          const float mn = fmaxf(m_, mx);
          const float scl = __expf(m_ - mn);
          m_ = mn;
          ld_ *= scl;
#pragma unroll
          for (int nt = 0; nt < 4; nt++) o[nt] *= scl;
        }
        float a = 0.0f;
#pragma unroll
        for (int nt = 0; nt < 4; nt++)
#pragma unroll
          for (int i = 0; i < 4; i++) {
            const float p = __expf(s[nt][i] - m_);
            s[nt][i] = p;
            a += p;
          }
        a += __shfl_xor(a, 16, 64);
        a += __shfl_xor(a, 32, 64);
        ld_ += a;

        bf16x8 pb0, pb1;
        pack_bfly(s, lg, pb0, pb1);

        // PV: O^T[d][q] += V^T[d][k] * P^T[k][q]
#pragma unroll
        for (int nt = 0; nt < 4; nt++) {
          const int vrow = nt * 16 + lr;
          const int vsw = (vrow & 7) << 4;
          bf16x8 vf0 = *reinterpret_cast<const bf16x8*>(Vb + vrow * 128 + ((lg * 16) ^ vsw));
          bf16x8 vf1 = *reinterpret_cast<const bf16x8*>(Vb + vrow * 128 + ((64 + lg * 16) ^ vsw));
          o[nt] = MFMA16(vf0, pb0, o[nt]);
          o[nt] = MFMA16(vf1, pb1, o[nt]);
        }
      }
    }
    __builtin_amdgcn_s_barrier();  // protect buf[cur] before next prefetch
  }

  // epilogue: o^T[d = nt*16+lg*4+i][q = lr], normalize, 8B vector stores
  const float rinv = 1.0f / ld_;
#pragma unroll
  for (int nt = 0; nt < 4; nt++) {
    bf16x4 r = {(bf16_t)(o[nt][0] * rinv), (bf16_t)(o[nt][1] * rinv),
                (bf16_t)(o[nt][2] * rinv), (bf16_t)(o[nt][3] * rinv)};
    *reinterpret_cast<bf16x4*>(outp + (size_t)(b * 1024 + qrow_l) * 1024 + h * 64 + nt * 16 + lg * 4) = r;
  }
}

// ---------------------------------------------------------------------------
extern "C" void kernel_launch(void* const* d_in, const int* in_sizes, int n_in,
                              void* d_out, int out_size, void* d_ws, size_t ws_size,
                              hipStream_t stream) {
  const float* q   = (const float*)d_in[0];
  const float* k   = (const float*)d_in[1];
  const float* v   = (const float*)d_in[2];
  const int*   pad = (const int*)d_in[3];
  const float* wq  = (const float*)d_in[5];
  const float* bq  = (const float*)d_in[6];
  const float* wk  = (const float*)d_in[7];
  const float* wv  = (const float*)d_in[8];
  const float* bv  = (const float*)d_in[9];
  const float* wo  = (const float*)d_in[10];
  const float* bo  = (const float*)d_in[11];

  const int M = 8192, N = 1024;
  const int nBig = M * N;
  const int nW   = N * 1024;

  char* ws = (char*)d_ws;
  const size_t MiB = 1024 * 1024;
  bf16_t* qbf = (bf16_t*)(ws + 0 * MiB);
  bf16_t* kbf = (bf16_t*)(ws + 16 * MiB);
  bf16_t* vbf = (bf16_t*)(ws + 32 * MiB);
  bf16_t* qp  = (bf16_t*)(ws + 48 * MiB);
  bf16_t* kp  = (bf16_t*)(ws + 64 * MiB);
  bf16_t* vtw = (bf16_t*)(ws + 80 * MiB);
  bf16_t* wqb = (bf16_t*)(ws + 96 * MiB);
  bf16_t* wkb = (bf16_t*)(ws + 98 * MiB);
  bf16_t* wvb = (bf16_t*)(ws + 100 * MiB);
  bf16_t* wob = (bf16_t*)(ws + 102 * MiB);
  bf16_t* attnO = qbf;  // qbf dead after q-projection

  cvt_qkv<<<dim3(nBig / 2048, 3), 256, 0, stream>>>(q, k, v, qbf, kbf, vbf, nBig / 8);
  cvt_w4 <<<dim3(nW / 2048, 4), 256, 0, stream>>>(wq, wk, wv, wo, wqb, wkb, wvb, wob, nW / 8);

  gemm_qkv<<<dim3(512, 3), 256, 0, stream>>>(qbf, kbf, vbf, wqb, wkb, wvb, bq, bv, qp, kp, vtw);

  attn_fused<<<1024, 512, 0, stream>>>(qp, kp, vtw, pad, attnO);

  gemm_out<<<512, 256, 0, stream>>>(attnO, wob, bo, (float*)d_out);
}

// Round 6
// 189.795 us; speedup vs baseline: 1.3251x; 1.0616x over previous
//
#include <hip/hip_runtime.h>
#include <hip/hip_bf16.h>
#include <cstdint>
#include <math.h>

// ---------------------------------------------------------------------------
// MyMultiHeadAttention: q/k/v proj (merged bf16 MFMA GEMM, 2-phase dbuf,
// XCD panel swizzle, q pre-scaled by 1/8, coalesced vt epilogue) -> fused
// flash attention (paired causal q-tiles, 8 waves, swapped QK^T, in-register
// softmax+P, exact -1e9 semantics) -> output proj (f32 out).
// B=8 S=1024 D=1024 H=16 Dh=64.
// ---------------------------------------------------------------------------

typedef __bf16 bf16_t;
typedef __bf16 bf16x8 __attribute__((ext_vector_type(8)));
typedef __bf16 bf16x4 __attribute__((ext_vector_type(4)));
typedef float  f32x4  __attribute__((ext_vector_type(4)));

#define MFMA16(a, b, c) __builtin_amdgcn_mfma_f32_16x16x32_bf16((a), (b), (c), 0, 0, 0)
#define NEGV (-1e9f)

__device__ __forceinline__ void gl_lds16(const void* gp, void* lp) {
  __builtin_amdgcn_global_load_lds(
      (__attribute__((address_space(1))) void*)(gp),
      (__attribute__((address_space(3))) void*)(lp), 16, 0, 0);
}

__device__ __forceinline__ unsigned int pk2(float lo, float hi) {
  unsigned short a = __builtin_bit_cast(unsigned short, (bf16_t)lo);
  unsigned short b = __builtin_bit_cast(unsigned short, (bf16_t)hi);
  return (unsigned int)a | ((unsigned int)b << 16);
}

// ---------------- f32 -> bf16 bulk converts (8 elems/thread) ----------------
__device__ __forceinline__ void cvt_body(const float* __restrict__ in,
                                         bf16_t* __restrict__ out, int i, int n8) {
  if (i < n8) {
    const float4* p = reinterpret_cast<const float4*>(in) + (size_t)i * 2;
    float4 a = p[0], b = p[1];
    bf16x8 r = {(bf16_t)a.x, (bf16_t)a.y, (bf16_t)a.z, (bf16_t)a.w,
                (bf16_t)b.x, (bf16_t)b.y, (bf16_t)b.z, (bf16_t)b.w};
    *reinterpret_cast<bf16x8*>(out + (size_t)i * 8) = r;
  }
}

__global__ __launch_bounds__(256) void cvt_qkv(const float* __restrict__ a, const float* __restrict__ b,
                                               const float* __restrict__ c,
                                               bf16_t* __restrict__ oa, bf16_t* __restrict__ ob,
                                               bf16_t* __restrict__ oc, int n8) {
  const float* in = blockIdx.y == 0 ? a : (blockIdx.y == 1 ? b : c);
  bf16_t* out     = blockIdx.y == 0 ? oa : (blockIdx.y == 1 ? ob : oc);
  cvt_body(in, out, blockIdx.x * 256 + threadIdx.x, n8);
}

__global__ __launch_bounds__(256) void cvt_w4(const float* __restrict__ a, const float* __restrict__ b,
                                              const float* __restrict__ c, const float* __restrict__ d,
                                              bf16_t* __restrict__ oa, bf16_t* __restrict__ ob,
                                              bf16_t* __restrict__ oc, bf16_t* __restrict__ od, int n8) {
  const float* in = blockIdx.y == 0 ? a : (blockIdx.y == 1 ? b : (blockIdx.y == 2 ? c : d));
  bf16_t* out     = blockIdx.y == 0 ? oa : (blockIdx.y == 1 ? ob : (blockIdx.y == 2 ? oc : od));
  cvt_body(in, out, blockIdx.x * 256 + threadIdx.x, n8);
}

// ---- XCD panel swizzle: 8 N-tiles of one M-panel land on one XCD ----------
__device__ __forceinline__ void panel_decode(int r, int& bx, int& by) {
  const int t8 = r >> 3;
  bx = t8 & 7;
  by = ((t8 >> 3) << 3) | (r & 7);
}

// ---------------- merged q/k/v projection GEMM (2-phase dbuf) ---------------
// grid (512, 3): z=0 q-proj (bias, x0.125), z=1 k-proj, z=2 v-proj (vt via
// LDS-bounce coalesced epilogue).  C[m,n] = sum_k A[m,k]*W[n,k].
__global__ __launch_bounds__(256) void gemm_qkv(const bf16_t* __restrict__ qbf,
                                                const bf16_t* __restrict__ kbf,
                                                const bf16_t* __restrict__ vbf,
                                                const bf16_t* __restrict__ wqb,
                                                const bf16_t* __restrict__ wkb,
                                                const bf16_t* __restrict__ wvb,
                                                const float* __restrict__ bq,
                                                const float* __restrict__ bv,
                                                bf16_t* __restrict__ qp,
                                                bf16_t* __restrict__ kp,
                                                bf16_t* __restrict__ vtw) {
  __shared__ bf16_t smem[4][128 * 32];  // [0..1]=A dbuf, [2..3]=B dbuf (32 KiB)
  const int z = blockIdx.y;
  const bf16_t* A = z == 0 ? qbf : (z == 1 ? kbf : vbf);
  const bf16_t* W = z == 0 ? wqb : (z == 1 ? wkb : wvb);
  const int t = threadIdx.x;
  const int w = t >> 6, l = t & 63, lr = l & 15, lg = l >> 4;
  int bx, by;
  panel_decode((int)blockIdx.x, bx, by);
  const int m0 = by * 128, n0 = bx * 128;
  const int wm = (w >> 1) * 64, wn = (w & 1) * 64;
  const int K = 1024, N = 1024;

  f32x4 acc[4][4] = {};
  const bf16_t* Ag = A + (size_t)(m0 + (t >> 2)) * K + (t & 3) * 8;
  const bf16_t* Wg = W + (size_t)(n0 + (t >> 2)) * K + (t & 3) * 8;

  auto stage = [&](int buf, int kt) {
    gl_lds16(Ag + kt,                  (char*)(smem[buf])     + t * 16);
    gl_lds16(Ag + kt + (size_t)64 * K, (char*)(smem[buf])     + 4096 + t * 16);
    gl_lds16(Wg + kt,                  (char*)(smem[2 + buf]) + t * 16);
    gl_lds16(Wg + kt + (size_t)64 * K, (char*)(smem[2 + buf]) + 4096 + t * 16);
  };

  stage(0, 0);
  __syncthreads();  // implicit vmcnt(0) drain of prologue staging

  for (int it = 0; it < 32; ++it) {
    const int cur = it & 1;
    if (it < 31) stage(cur ^ 1, (it + 1) * 32);  // prefetch overlaps compute

    const char* AsB = (const char*)(smem[cur]);
    const char* BsB = (const char*)(smem[2 + cur]);
    bf16x8 af[4], bfr[4];
#pragma unroll
    for (int mt = 0; mt < 4; mt++)
      af[mt] = *reinterpret_cast<const bf16x8*>(AsB + ((wm + mt * 16 + lr) * 32 + lg * 8) * 2);
#pragma unroll
    for (int nt = 0; nt < 4; nt++)
      bfr[nt] = *reinterpret_cast<const bf16x8*>(BsB + ((wn + nt * 16 + lr) * 32 + lg * 8) * 2);
#pragma unroll
    for (int mt = 0; mt < 4; mt++)
#pragma unroll
      for (int nt = 0; nt < 4; nt++)
        acc[mt][nt] = MFMA16(af[mt], bfr[nt], acc[mt][nt]);
    __syncthreads();  // implicit vmcnt(0)+lgkmcnt(0): prefetch landed, reads done
  }

  if (z != 2) {
    bf16_t* outp = (z == 0) ? qp : kp;
    const float sc = (z == 0) ? 0.125f : 1.0f;  // fold attention's /8 (exact)
#pragma unroll
    for (int nt = 0; nt < 4; nt++) {
      const int col = n0 + wn + nt * 16 + lr;
      const float bb = (z == 0) ? bq[col] : 0.0f;
#pragma unroll
      for (int mt = 0; mt < 4; mt++)
#pragma unroll
        for (int i = 0; i < 4; i++) {
          const int row = m0 + wm + mt * 16 + lg * 4 + i;
          outp[(size_t)row * N + col] = (bf16_t)((acc[mt][nt][i] + bb) * sc);
        }
    }
  } else {
    // vt epilogue: C^T -> LDS (16B-chunk XOR swizzle) -> coalesced 128B rows.
    // vt row index = b*1024 + n0 + col_l; s = m0&1023 + row_l.
    char* T = (char*)smem;  // 32 KiB, K-loop done
#pragma unroll
    for (int nt = 0; nt < 4; nt++) {
      const int col_l = wn + nt * 16 + lr;
      const float bb = bv[n0 + col_l];
#pragma unroll
      for (int mt = 0; mt < 4; mt++)
#pragma unroll
        for (int i = 0; i < 4; i++) {
          const int row_l = wm + mt * 16 + lg * 4 + i;
          *(bf16_t*)(T + col_l * 256 + ((row_l * 2) ^ ((col_l & 7) << 4))) =
              (bf16_t)(acc[mt][nt][i] + bb);
        }
    }
    __syncthreads();
    const int b = m0 >> 10, s0 = m0 & 1023;
    const int c_l = t >> 1, half = t & 1;
    bf16_t* dst = vtw + (size_t)(b * 1024 + n0 + c_l) * 1024 + s0 + half * 64;
    const char* Trow = T + c_l * 256;
    const int sw = c_l & 7;
#pragma unroll
    for (int jj = 0; jj < 8; jj++) {
      const int lc = half * 8 + jj;
      bf16x8 vv = *reinterpret_cast<const bf16x8*>(Trow + ((lc ^ sw) << 4));
      *reinterpret_cast<bf16x8*>(dst + jj * 8) = vv;
    }
  }
}

// ---------------- final GEMM: f32 out, bias, 2-phase dbuf ----------------
__global__ __launch_bounds__(256) void gemm_out(const bf16_t* __restrict__ A,
                                                const bf16_t* __restrict__ W,
                                                const float* __restrict__ bias,
                                                float* __restrict__ outp) {
  __shared__ bf16_t smem[4][128 * 32];
  const int t = threadIdx.x;
  const int w = t >> 6, l = t & 63, lr = l & 15, lg = l >> 4;
  int bx, by;
  panel_decode((int)blockIdx.x, bx, by);
  const int m0 = by * 128, n0 = bx * 128;
  const int wm = (w >> 1) * 64, wn = (w & 1) * 64;
  const int K = 1024, N = 1024;

  f32x4 acc[4][4] = {};
  const bf16_t* Ag = A + (size_t)(m0 + (t >> 2)) * K + (t & 3) * 8;
  const bf16_t* Wg = W + (size_t)(n0 + (t >> 2)) * K + (t & 3) * 8;

  auto stage = [&](int buf, int kt) {
    gl_lds16(Ag + kt,                  (char*)(smem[buf])     + t * 16);
    gl_lds16(Ag + kt + (size_t)64 * K, (char*)(smem[buf])     + 4096 + t * 16);
    gl_lds16(Wg + kt,                  (char*)(smem[2 + buf]) + t * 16);
    gl_lds16(Wg + kt + (size_t)64 * K, (char*)(smem[2 + buf]) + 4096 + t * 16);
  };

  stage(0, 0);
  __syncthreads();

  for (int it = 0; it < 32; ++it) {
    const int cur = it & 1;
    if (it < 31) stage(cur ^ 1, (it + 1) * 32);

    const char* AsB = (const char*)(smem[cur]);
    const char* BsB = (const char*)(smem[2 + cur]);
    bf16x8 af[4], bfr[4];
#pragma unroll
    for (int mt = 0; mt < 4; mt++)
      af[mt] = *reinterpret_cast<const bf16x8*>(AsB + ((wm + mt * 16 + lr) * 32 + lg * 8) * 2);
#pragma unroll
    for (int nt = 0; nt < 4; nt++)
      bfr[nt] = *reinterpret_cast<const bf16x8*>(BsB + ((wn + nt * 16 + lr) * 32 + lg * 8) * 2);
#pragma unroll
    for (int mt = 0; mt < 4; mt++)
#pragma unroll
      for (int nt = 0; nt < 4; nt++)
        acc[mt][nt] = MFMA16(af[mt], bfr[nt], acc[mt][nt]);
    __syncthreads();
  }

#pragma unroll
  for (int nt = 0; nt < 4; nt++) {
    const int col = n0 + wn + nt * 16 + lr;
    const float bb = bias[col];
#pragma unroll
    for (int mt = 0; mt < 4; mt++)
#pragma unroll
      for (int i = 0; i < 4; i++) {
        const int row = m0 + wm + mt * 16 + lg * 4 + i;
        outp[(size_t)row * N + col] = acc[mt][nt][i] + bb;
      }
  }
}

// ---------------- in-register P pack + butterfly (16-lane groups) ----------
__device__ __forceinline__ void pack_bfly(const f32x4 (&s)[4], int lg,
                                          bf16x8& pbv0, bf16x8& pbv1) {
  unsigned int u[4][2], sh[4][2];
#pragma unroll
  for (int nt = 0; nt < 4; nt++) {
    u[nt][0] = pk2(s[nt][0], s[nt][1]);
    u[nt][1] = pk2(s[nt][2], s[nt][3]);
  }
#pragma unroll
  for (int nt = 0; nt < 4; nt++) {
    sh[nt][0] = (unsigned int)__shfl_xor((int)u[nt][0], 16, 64);
    sh[nt][1] = (unsigned int)__shfl_xor((int)u[nt][1], 16, 64);
  }
  const bool ev = (lg & 1) == 0;
  unsigned int Y[8];
  Y[0] = ev ? u[0][0] : sh[1][0];  Y[1] = ev ? u[0][1] : sh[1][1];
  Y[2] = ev ? u[2][0] : sh[3][0];  Y[3] = ev ? u[2][1] : sh[3][1];
  Y[4] = ev ? sh[0][0] : u[1][0];  Y[5] = ev ? sh[0][1] : u[1][1];
  Y[6] = ev ? sh[2][0] : u[3][0];  Y[7] = ev ? sh[2][1] : u[3][1];
  const bool mid = (lg == 1) || (lg == 2);
#pragma unroll
  for (int j = 0; j < 8; j++) {
    const unsigned int z = (unsigned int)__shfl_xor((int)Y[j], 48, 64);
    Y[j] = mid ? z : Y[j];
  }
  union U8 { unsigned int u[4]; bf16x8 v; };
  U8 p0, p1;
  p0.u[0] = Y[0]; p0.u[1] = Y[1]; p0.u[2] = Y[4]; p0.u[3] = Y[5];
  p1.u[0] = Y[2]; p1.u[1] = Y[3]; p1.u[2] = Y[6]; p1.u[3] = Y[7];
  pbv0 = p0.v;
  pbv1 = p1.v;
}

// ---------------- fused flash attention (paired q-tiles, 8 waves) ----------
// Grid 1024: bh = (L&7)+8*(L>>6) (16 bh/XCD), j = (L>>3)&7.
// Block handles q-tiles lo=j (waves 4-7) and hi=15-j (waves 0-3), sharing one
// K/V staging stream over k-tiles 0..hi.  qp pre-scaled by 0.125 (exact).
__global__ __launch_bounds__(512, 8) void attn_fused(const bf16_t* __restrict__ qp,
                                                     const bf16_t* __restrict__ kp,
                                                     const bf16_t* __restrict__ vt,
                                                     const int* __restrict__ pad,
                                                     bf16_t* __restrict__ outp) {
  __shared__ bf16_t Ks[2][64 * 64];   // [key][dh], XOR-swizzled
  __shared__ bf16_t Vts[2][64 * 64];  // [dh][key], XOR-swizzled
  __shared__ int padI[1024];
  __shared__ int sfl[8], sfh[8];
  const int t = threadIdx.x, w = t >> 6, l = t & 63, lr = l & 15, lg = l >> 4;
  const int L = (int)blockIdx.x;
  const int bh = (L & 7) + ((L >> 6) << 3);
  const int j = (L >> 3) & 7;
  const int b = bh >> 4, h = bh & 15;
  const int lo = j, hi = 15 - j;

  const int srow = t >> 3, sc = t & 7;
  const int gc = sc ^ (srow & 7);  // pre-swizzled global chunk
  const bf16_t* kgb = kp + (size_t)(b * 1024 + srow) * 1024 + h * 64 + gc * 8;
  const bf16_t* vgb = vt + (size_t)(bh * 64 + srow) * 1024 + gc * 8;

  auto stage = [&](int bufi, int k0s) {
    gl_lds16(kgb + (size_t)k0s * 1024, (char*)(Ks[bufi]) + t * 16);
    gl_lds16(vgb + k0s,                (char*)(Vts[bufi]) + t * 16);
  };

  // degenerate-row checks: any unpadded key in [0, lo*64] / [0, hi*64]?
  bool unl = false, unh = false;
  for (int jj = t; jj <= hi * 64; jj += 512) {
    const bool u = (pad[b * 1024 + jj] == 0);
    unh |= u;
    unl |= (u && (jj <= lo * 64));
  }
  const bool al = __any(unl), ah = __any(unh);
  if (l == 0) { sfl[w] = al ? 1 : 0; sfh[w] = ah ? 1 : 0; }

  stage(0, 0);
  if (t < 256) gl_lds16(pad + b * 1024 + t * 4, (char*)padI + t * 16);

  // this wave's q-tile: waves 0-3 -> hi, waves 4-7 -> lo
  const int mytile = (w < 4) ? hi : lo;
  const int qrow_l = mytile * 64 + (w & 3) * 16 + lr;  // lane's q row
  const int base16 = mytile * 64 + (w & 3) * 16;
  const bf16_t* qg = qp + (size_t)(b * 1024 + qrow_l) * 1024 + h * 64 + lg * 8;
  const bf16x8 qa0 = *reinterpret_cast<const bf16x8*>(qg);
  const bf16x8 qa1 = *reinterpret_cast<const bf16x8*>(qg + 32);

  __syncthreads();  // sf ready; drains tile-0 staging + padI
  int ul = 0, uh = 0;
#pragma unroll
  for (int i = 0; i < 8; i++) { ul |= sfl[i]; uh |= sfh[i]; }
  const bool mydeg = (w < 4) ? (uh == 0) : (ul == 0);
  const int ktEnd = (ul == 0) ? 16 : (hi + 1);

  f32x4 o[4] = {};
  float m_ = -INFINITY, ld_ = 0.0f;

  for (int kt = 0; kt < ktEnd; ++kt) {
    const int cur = kt & 1;
    if (kt + 1 < ktEnd) {
      stage(cur ^ 1, (kt + 1) * 64);
      asm volatile("s_waitcnt vmcnt(2)" ::: "memory");
    } else {
      asm volatile("s_waitcnt vmcnt(0)" ::: "memory");
    }
    __builtin_amdgcn_s_barrier();

    if (kt <= mytile || mydeg) {
      const char* Kb = (const char*)(Ks[cur]);
      const char* Vb = (const char*)(Vts[cur]);
      const int k0 = kt * 64;

      // S^T = K * Q^T : s[nt][i] = score[key=k0+nt*16+lg*4+i][q=qrow_l]
      f32x4 s[4] = {};
#pragma unroll
      for (int nt = 0; nt < 4; nt++) {
        const int row = nt * 16 + lr;
        const int sw = (row & 7) << 4;
        bf16x8 kb0 = *reinterpret_cast<const bf16x8*>(Kb + row * 128 + ((lg * 16) ^ sw));
        bf16x8 kb1 = *reinterpret_cast<const bf16x8*>(Kb + row * 128 + ((lg * 16 + 64) ^ sw));
        s[nt] = MFMA16(kb0, qa0, s[nt]);
        s[nt] = MFMA16(kb1, qa1, s[nt]);
      }

      // masking — reference f32 arithmetic exactly (qp pre-scaled by 1/8)
      const bool nc = (k0 + 63 > base16);
#pragma unroll
      for (int nt = 0; nt < 4; nt++) {
        const int kc4 = k0 + nt * 16 + lg * 4;
        const int4 pd = *reinterpret_cast<const int4*>(&padI[kc4]);
        const int pdv[4] = {pd.x, pd.y, pd.z, pd.w};
#pragma unroll
        for (int i = 0; i < 4; i++) {
          float v = s[nt][i];
          if (pdv[i]) v = NEGV;
          if (nc && (kc4 + i > qrow_l)) v += NEGV;
          s[nt][i] = v;
        }
      }

      // row max: 15 reg-local fmax + 2 shfl
      float mx = s[0][0];
#pragma unroll
      for (int nt = 0; nt < 4; nt++)
#pragma unroll
        for (int i = 0; i < 4; i++) mx = fmaxf(mx, s[nt][i]);
      mx = fmaxf(mx, __shfl_xor(mx, 16, 64));
      mx = fmaxf(mx, __shfl_xor(mx, 32, 64));

      if (!__all(mx <= m_ - 88.0f)) {          // dynamic underflow skip
        if (!__all(mx <= m_ + 8.0f)) {         // defer-max rescale
          const float mn = fmaxf(m_, mx);
          const float scl = __expf(m_ - mn);
          m_ = mn;
          ld_ *= scl;
#pragma unroll
          for (int nt = 0; nt < 4; nt++) o[nt] *= scl;
        }
        float a = 0.0f;
#pragma unroll
        for (int nt = 0; nt < 4; nt++)
#pragma unroll
          for (int i = 0; i < 4; i++) {
            const float p = __expf(s[nt][i] - m_);
            s[nt][i] = p;
            a += p;
          }
        a += __shfl_xor(a, 16, 64);
        a += __shfl_xor(a, 32, 64);
        ld_ += a;

        bf16x8 pb0, pb1;
        pack_bfly(s, lg, pb0, pb1);

        // PV: O^T[d][q] += V^T[d][k] * P^T[k][q]
#pragma unroll
        for (int nt = 0; nt < 4; nt++) {
          const int vrow = nt * 16 + lr;
          const int vsw = (vrow & 7) << 4;
          bf16x8 vf0 = *reinterpret_cast<const bf16x8*>(Vb + vrow * 128 + ((lg * 16) ^ vsw));
          bf16x8 vf1 = *reinterpret_cast<const bf16x8*>(Vb + vrow * 128 + ((64 + lg * 16) ^ vsw));
          o[nt] = MFMA16(vf0, pb0, o[nt]);
          o[nt] = MFMA16(vf1, pb1, o[nt]);
        }
      }
    }
    __builtin_amdgcn_s_barrier();  // protect buf[cur] before next prefetch
  }

  // epilogue: o^T[d = nt*16+lg*4+i][q = lr], normalize, 8B vector stores
  const float rinv = 1.0f / ld_;
#pragma unroll
  for (int nt = 0; nt < 4; nt++) {
    bf16x4 r = {(bf16_t)(o[nt][0] * rinv), (bf16_t)(o[nt][1] * rinv),
                (bf16_t)(o[nt][2] * rinv), (bf16_t)(o[nt][3] * rinv)};
    *reinterpret_cast<bf16x4*>(outp + (size_t)(b * 1024 + qrow_l) * 1024 + h * 64 + nt * 16 + lg * 4) = r;
  }
}

// ---------------------------------------------------------------------------
extern "C" void kernel_launch(void* const* d_in, const int* in_sizes, int n_in,
                              void* d_out, int out_size, void* d_ws, size_t ws_size,
                              hipStream_t stream) {
  const float* q   = (const float*)d_in[0];
  const float* k   = (const float*)d_in[1];
  const float* v   = (const float*)d_in[2];
  const int*   pad = (const int*)d_in[3];
  const float* wq  = (const float*)d_in[5];
  const float* bq  = (const float*)d_in[6];
  const float* wk  = (const float*)d_in[7];
  const float* wv  = (const float*)d_in[8];
  const float* bv  = (const float*)d_in[9];
  const float* wo  = (const float*)d_in[10];
  const float* bo  = (const float*)d_in[11];

  const int M = 8192, N = 1024;
  const int nBig = M * N;
  const int nW   = N * 1024;

  char* ws = (char*)d_ws;
  const size_t MiB = 1024 * 1024;
  bf16_t* qbf = (bf16_t*)(ws + 0 * MiB);
  bf16_t* kbf = (bf16_t*)(ws + 16 * MiB);
  bf16_t* vbf = (bf16_t*)(ws + 32 * MiB);
  bf16_t* qp  = (bf16_t*)(ws + 48 * MiB);
  bf16_t* kp  = (bf16_t*)(ws + 64 * MiB);
  bf16_t* vtw = (bf16_t*)(ws + 80 * MiB);
  bf16_t* wqb = (bf16_t*)(ws + 96 * MiB);
  bf16_t* wkb = (bf16_t*)(ws + 98 * MiB);
  bf16_t* wvb = (bf16_t*)(ws + 100 * MiB);
  bf16_t* wob = (bf16_t*)(ws + 102 * MiB);
  bf16_t* attnO = qbf;  // qbf dead after q-projection

  cvt_qkv<<<dim3(nBig / 2048, 3), 256, 0, stream>>>(q, k, v, qbf, kbf, vbf, nBig / 8);
  cvt_w4 <<<dim3(nW / 2048, 4), 256, 0, stream>>>(wq, wk, wv, wo, wqb, wkb, wvb, wob, nW / 8);

  gemm_qkv<<<dim3(512, 3), 256, 0, stream>>>(qbf, kbf, vbf, wqb, wkb, wvb, bq, bv, qp, kp, vtw);

  attn_fused<<<1024, 512, 0, stream>>>(qp, kp, vtw, pad, attnO);

  gemm_out<<<512, 256, 0, stream>>>(attnO, wob, bo, (float*)d_out);
}